// Round 3
// baseline (398.382 us; speedup 1.0000x reference)
//
#include <hip/hip_runtime.h>
#include <hip/hip_bf16.h>

#define NNODES 100000
#define DIN 128
#define DH 64
#define SRCMASK 0x1FFFF    // N < 2^17
#define NODECAP 64         // slots per node (Poisson(32); overflow -> fixup list)
#define OVFCAP 1024

typedef short s16x8 __attribute__((ext_vector_type(8)));
typedef float f32x4 __attribute__((ext_vector_type(4)));

static __device__ __forceinline__ short f2bf(float f) {
  __hip_bfloat16 h = __float2bfloat16(f);   // RTNE
  return *reinterpret_cast<short*>(&h);
}
static __device__ __forceinline__ float bf2f(short s) {
  return __uint_as_float(((unsigned)(unsigned short)s) << 16);
}

// ---------------- dense transforms via MFMA (hi/lo bf16 split ~ 17-bit mantissa) ----------------
// mfma_f32_16x16x32_bf16 layouts (m89-verified):
//   A: row = lane&15, k = (lane>>4)*8 + i
//   B: col = lane&15, k = (lane>>4)*8 + i
//   D: col = lane&15, row = (lane>>4)*4 + reg

__global__ __launch_bounds__(256, 4) void gemm1_mfma(
    const float* __restrict__ emb, const float* __restrict__ W1,
    __hip_bfloat16* __restrict__ x1, int N) {
  __shared__ short Bhi[4 * 4 * 64 * 8];   // [kc][ct][lane][8] = 8192 bf16 = 16 KB
  __shared__ short Blo[4 * 4 * 64 * 8];   // 16 KB
  int tid = threadIdx.x;

  for (int idx = tid; idx < 8192; idx += 256) {
    int i = idx & 7, ln = (idx >> 3) & 63, ct = (idx >> 9) & 3, kc = idx >> 11;
    int k = kc * 32 + (ln >> 4) * 8 + i;
    int col = ct * 16 + (ln & 15);
    float w = W1[k * DH + col];
    short h = f2bf(w);
    Bhi[idx] = h;
    Blo[idx] = f2bf(w - bf2f(h));
  }
  __syncthreads();

  int lane = tid & 63, wv = tid >> 6;
  int r0 = (blockIdx.x * 8 + wv * 2) * 16;   // this wave: rows r0 .. r0+31
  if (r0 >= N) return;

  const int rA = lane & 15, g = lane >> 4;
  f32x4 acc[2][4] = {};

#pragma unroll
  for (int kc = 0; kc < 4; ++kc) {
    s16x8 ahi[2], alo[2];
#pragma unroll
    for (int rt = 0; rt < 2; ++rt) {
      int r = r0 + rt * 16 + rA;
      float av[8];
      if (r < N) {
        const float4* ap = (const float4*)(emb + (long)r * DIN + kc * 32 + g * 8);
        float4 v0 = ap[0], v1 = ap[1];
        av[0] = v0.x; av[1] = v0.y; av[2] = v0.z; av[3] = v0.w;
        av[4] = v1.x; av[5] = v1.y; av[6] = v1.z; av[7] = v1.w;
      } else {
#pragma unroll
        for (int i = 0; i < 8; ++i) av[i] = 0.f;
      }
#pragma unroll
      for (int i = 0; i < 8; ++i) {
        short h = f2bf(av[i]);
        ahi[rt][i] = h;
        alo[rt][i] = f2bf(av[i] - bf2f(h));
      }
    }
#pragma unroll
    for (int ct = 0; ct < 4; ++ct) {
      int fo = ((kc * 4 + ct) * 64 + lane) * 8;
      s16x8 bh = *(const s16x8*)&Bhi[fo];
      s16x8 bl = *(const s16x8*)&Blo[fo];
#pragma unroll
      for (int rt = 0; rt < 2; ++rt) {
        acc[rt][ct] = __builtin_amdgcn_mfma_f32_16x16x32_bf16(ahi[rt], bh, acc[rt][ct], 0, 0, 0);
        acc[rt][ct] = __builtin_amdgcn_mfma_f32_16x16x32_bf16(alo[rt], bh, acc[rt][ct], 0, 0, 0);
        acc[rt][ct] = __builtin_amdgcn_mfma_f32_16x16x32_bf16(ahi[rt], bl, acc[rt][ct], 0, 0, 0);
      }
    }
  }

#pragma unroll
  for (int rt = 0; rt < 2; ++rt) {
#pragma unroll
    for (int j = 0; j < 4; ++j) {
      int row = r0 + rt * 16 + g * 4 + j;
      if (row < N) {
#pragma unroll
        for (int ct = 0; ct < 4; ++ct)
          x1[(long)row * DH + ct * 16 + rA] = __float2bfloat16(acc[rt][ct][j]);
      }
    }
  }
}

__global__ __launch_bounds__(256, 4) void gemm2_mfma(
    const float* __restrict__ agg, const float* __restrict__ W2,
    const float* __restrict__ b1, __hip_bfloat16* __restrict__ x2, int N) {
  __shared__ short Bhi[2 * 4 * 64 * 8];   // 4096 bf16 = 8 KB
  __shared__ short Blo[2 * 4 * 64 * 8];   // 8 KB
  int tid = threadIdx.x;

  for (int idx = tid; idx < 4096; idx += 256) {
    int i = idx & 7, ln = (idx >> 3) & 63, ct = (idx >> 9) & 3, kc = (idx >> 11) & 1;
    int k = kc * 32 + (ln >> 4) * 8 + i;
    int col = ct * 16 + (ln & 15);
    float w = W2[k * DH + col];
    short h = f2bf(w);
    Bhi[idx] = h;
    Blo[idx] = f2bf(w - bf2f(h));
  }
  __syncthreads();

  int lane = tid & 63, wv = tid >> 6;
  int r0 = (blockIdx.x * 8 + wv * 2) * 16;
  if (r0 >= N) return;

  const int rA = lane & 15, g = lane >> 4;
  f32x4 acc[2][4] = {};

#pragma unroll
  for (int kc = 0; kc < 2; ++kc) {
    const float4* bp = (const float4*)(b1 + kc * 32 + g * 8);
    float4 b0 = bp[0], b4 = bp[1];
    float bv[8] = {b0.x, b0.y, b0.z, b0.w, b4.x, b4.y, b4.z, b4.w};
    s16x8 ahi[2], alo[2];
#pragma unroll
    for (int rt = 0; rt < 2; ++rt) {
      int r = r0 + rt * 16 + rA;
      float av[8];
      if (r < N) {
        const float4* ap = (const float4*)(agg + (long)r * DH + kc * 32 + g * 8);
        float4 v0 = ap[0], v1 = ap[1];
        av[0] = v0.x; av[1] = v0.y; av[2] = v0.z; av[3] = v0.w;
        av[4] = v1.x; av[5] = v1.y; av[6] = v1.z; av[7] = v1.w;
      } else {
#pragma unroll
        for (int i = 0; i < 8; ++i) av[i] = -1e30f;  // relu() -> 0 anyway
      }
#pragma unroll
      for (int i = 0; i < 8; ++i) {
        float a = fmaxf(av[i] + bv[i], 0.f);
        short h = f2bf(a);
        ahi[rt][i] = h;
        alo[rt][i] = f2bf(a - bf2f(h));
      }
    }
#pragma unroll
    for (int ct = 0; ct < 4; ++ct) {
      int fo = ((kc * 4 + ct) * 64 + lane) * 8;
      s16x8 bh = *(const s16x8*)&Bhi[fo];
      s16x8 bl = *(const s16x8*)&Blo[fo];
#pragma unroll
      for (int rt = 0; rt < 2; ++rt) {
        acc[rt][ct] = __builtin_amdgcn_mfma_f32_16x16x32_bf16(ahi[rt], bh, acc[rt][ct], 0, 0, 0);
        acc[rt][ct] = __builtin_amdgcn_mfma_f32_16x16x32_bf16(alo[rt], bh, acc[rt][ct], 0, 0, 0);
        acc[rt][ct] = __builtin_amdgcn_mfma_f32_16x16x32_bf16(ahi[rt], bl, acc[rt][ct], 0, 0, 0);
      }
    }
  }

#pragma unroll
  for (int rt = 0; rt < 2; ++rt) {
#pragma unroll
    for (int j = 0; j < 4; ++j) {
      int row = r0 + rt * 16 + g * 4 + j;
      if (row < N) {
#pragma unroll
        for (int ct = 0; ct < 4; ++ct)
          x2[(long)row * DH + ct * 16 + rA] = __float2bfloat16(acc[rt][ct][j]);
      }
    }
  }
}

// ---------------- direct-binned adjacency build (replaces 4-kernel bucketed CSR) ----------------
// slot = atomicAdd(deg[dst]); pairs2[dst*64 + slot] = src(17b) | round(w*2^15)<<17.
// deg > 64 overflows into a tiny list, applied by ovf_fixup after each agg.

__global__ __launch_bounds__(256) void scatter_fill(
    const int* __restrict__ srcs, const int* __restrict__ dsts,
    const float* __restrict__ w, int* __restrict__ deg,
    int* __restrict__ pairs2, int2* __restrict__ ovf, int* __restrict__ ovfcnt,
    int E) {
  int t = blockIdx.x * 256 + threadIdx.x;
  int e0 = t * 4;
  if (e0 + 3 < E) {
    int4 s4 = ((const int4*)srcs)[t];
    int4 d4 = ((const int4*)dsts)[t];
    float4 w4 = ((const float4*)w)[t];
    int ss[4] = {s4.x, s4.y, s4.z, s4.w};
    int dd[4] = {d4.x, d4.y, d4.z, d4.w};
    float ww[4] = {w4.x, w4.y, w4.z, w4.w};
#pragma unroll
    for (int i = 0; i < 4; ++i) {
      int wq = (int)(ww[i] * 32768.f + 0.5f);
      if (wq > 32767) wq = 32767;
      int pk = (ss[i] & SRCMASK) | (wq << 17);
      int slot = atomicAdd(&deg[dd[i]], 1);
      if (slot < NODECAP) {
        pairs2[(dd[i] << 6) + slot] = pk;
      } else {
        int oi = atomicAdd(ovfcnt, 1);
        if (oi < OVFCAP) ovf[oi] = make_int2(pk, dd[i]);
      }
    }
  } else {
    for (int e = e0; e < E; ++e) {
      int wq = (int)(w[e] * 32768.f + 0.5f);
      if (wq > 32767) wq = 32767;
      int pk = (srcs[e] & SRCMASK) | (wq << 17);
      int d = dsts[e];
      int slot = atomicAdd(&deg[d], 1);
      if (slot < NODECAP) {
        pairs2[(d << 6) + slot] = pk;
      } else {
        int oi = atomicAdd(ovfcnt, 1);
        if (oi < OVFCAP) ovf[oi] = make_int2(pk, d);
      }
    }
  }
}

// applies overflow edges (deg > 64; ~never for Poisson(32)) after an agg pass
__global__ __launch_bounds__(256) void ovf_fixup(
    const int2* __restrict__ ovf, const int* __restrict__ ovfcnt,
    const short* __restrict__ x, float* __restrict__ out) {
  int cnt = *ovfcnt;
  if (cnt > OVFCAP) cnt = OVFCAP;
  int wid = (int)((blockIdx.x * 256 + threadIdx.x) >> 6);
  int lane = threadIdx.x & 63;
  int nw = (gridDim.x * 256) >> 6;
  for (int i = wid; i < cnt; i += nw) {
    int2 e = ovf[i];
    unsigned p = (unsigned)e.x;
    float wv = (float)(p >> 17) * (1.f / 32768.f);
    float xv = bf2f(x[(long)(p & SRCMASK) * DH + lane]);
    atomicAdd(&out[(long)e.y * DH + lane], wv * xv);
  }
}

// ---------------- aggregation: fixed-stride rows, deep-MLP gather ----------------
// lane = h*16 + fj : h = edge-of-quad (0..3), fj = feature-quad (0..15).
// One coalesced pairs2 row load (64 slots); first 32 edges issued unconditionally
// (8 gathers in flight); 16-edge conditional steps for deg in (32,64].
#define ACC4(P, XV)                                          \
  do {                                                       \
    float wv_ = (float)((P) >> 17) * (1.f / 32768.f);        \
    a0 += wv_ * __uint_as_float((XV).x << 16);               \
    a1 += wv_ * __uint_as_float((XV).x & 0xFFFF0000u);       \
    a2 += wv_ * __uint_as_float((XV).y << 16);               \
    a3 += wv_ * __uint_as_float((XV).y & 0xFFFF0000u);       \
  } while (0)

__global__ __launch_bounds__(256) void agg_quad(
    const int* __restrict__ pairs2, const int* __restrict__ deg,
    const uint2* __restrict__ x,   // 4×bf16 per element, 16 per node
    const float* __restrict__ bias, float* __restrict__ out, int N) {
  int wid = (int)(((long)blockIdx.x * 256 + threadIdx.x) >> 6);
  int lane = threadIdx.x & 63;
  if (wid >= N) return;
  int h = lane >> 4;        // edge within quad
  int fj = lane & 15;       // feature-quad index
  int m = deg[wid];
  if (m > NODECAP) m = NODECAP;
  int base = wid << 6;
  int pl = (lane < m) ? pairs2[base + lane] : 0;   // coalesced, padded (w=0)
  float a0 = 0.f, a1 = 0.f, a2 = 0.f, a3 = 0.f;

  // edges 0..31: 8 independent gathers in flight, unconditional
  unsigned pg[8];
#pragma unroll
  for (int g = 0; g < 8; ++g) pg[g] = (unsigned)__shfl(pl, g * 4 + h);
  uint2 xg[8];
#pragma unroll
  for (int g = 0; g < 8; ++g) xg[g] = x[(pg[g] & SRCMASK) * 16 + fj];
#pragma unroll
  for (int g = 0; g < 8; ++g) ACC4(pg[g], xg[g]);

  // edges 32..63: 16-edge steps, wave-uniform early exit
#pragma unroll
  for (int q = 32; q < 64; q += 16) {
    if (q >= m) break;
    unsigned p0 = (unsigned)__shfl(pl, q + h);
    unsigned p1 = (unsigned)__shfl(pl, q + 4 + h);
    unsigned p2 = (unsigned)__shfl(pl, q + 8 + h);
    unsigned p3 = (unsigned)__shfl(pl, q + 12 + h);
    uint2 y0 = x[(p0 & SRCMASK) * 16 + fj];
    uint2 y1 = x[(p1 & SRCMASK) * 16 + fj];
    uint2 y2 = x[(p2 & SRCMASK) * 16 + fj];
    uint2 y3 = x[(p3 & SRCMASK) * 16 + fj];
    ACC4(p0, y0); ACC4(p1, y1); ACC4(p2, y2); ACC4(p3, y3);
  }

  // sum over the 4 edge-groups (h); lanes with equal fj hold same features
  a0 += __shfl_xor(a0, 16); a0 += __shfl_xor(a0, 32);
  a1 += __shfl_xor(a1, 16); a1 += __shfl_xor(a1, 32);
  a2 += __shfl_xor(a2, 16); a2 += __shfl_xor(a2, 32);
  a3 += __shfl_xor(a3, 16); a3 += __shfl_xor(a3, 32);
  if (lane < 16) {
    if (bias) {
      float4 bv = ((const float4*)bias)[fj];
      a0 += bv.x; a1 += bv.y; a2 += bv.z; a3 += bv.w;
    }
    ((float4*)out)[(long)wid * 16 + fj] = make_float4(a0, a1, a2, a3);
  }
}

// ---------------- fallback kernels (R1 atomic path, f32) ----------------

__global__ __launch_bounds__(256) void gemm1_f32(
    const float* __restrict__ emb, const float* __restrict__ W1,
    float* __restrict__ x1, int N) {
  __shared__ float Ws[DIN * DH];
  __shared__ float rows[4][DIN];
  int tid = threadIdx.x;
  for (int i = tid; i < DIN * DH; i += 256) Ws[i] = W1[i];
  int r0 = blockIdx.x * 4;
  for (int i = tid; i < 4 * DIN; i += 256) {
    int rr = i >> 7, kk = i & 127;
    int r = r0 + rr;
    rows[rr][kk] = (r < N) ? emb[(long)r * DIN + kk] : 0.f;
  }
  __syncthreads();
  int rr = tid >> 6, j = tid & 63;
  int r = r0 + rr;
  float acc = 0.f;
#pragma unroll
  for (int k = 0; k < DIN; ++k) acc += rows[rr][k] * Ws[k * DH + j];
  if (r < N) x1[(long)r * DH + j] = acc;
}

__global__ __launch_bounds__(256) void gemm2_f32(
    const float* __restrict__ agg, const float* __restrict__ W2,
    const float* __restrict__ b1, float* __restrict__ x2, int N) {
  __shared__ float Ws[DH * DH];
  __shared__ float rows[4][DH];
  int tid = threadIdx.x;
  for (int i = tid; i < DH * DH; i += 256) Ws[i] = W2[i];
  int r0 = blockIdx.x * 4;
  {
    int rr = tid >> 6, kk = tid & 63;
    int r = r0 + rr;
    float v = (r < N) ? agg[(long)r * DH + kk] + b1[kk] : 0.f;
    rows[rr][kk] = v > 0.f ? v : 0.f;
  }
  __syncthreads();
  int rr = tid >> 6, j = tid & 63;
  float acc = 0.f;
#pragma unroll
  for (int k = 0; k < DH; ++k) acc += rows[rr][k] * Ws[k * DH + j];
  int r = r0 + rr;
  if (r < N) x2[(long)r * DH + j] = acc;
}

__global__ __launch_bounds__(256) void init_bias_kernel(
    float* __restrict__ out, const float* __restrict__ b2, int total) {
  int i = blockIdx.x * 256 + threadIdx.x;
  if (i < total) out[i] = b2[i & 63];
}

__global__ __launch_bounds__(256) void scatter_kernel(
    const int* __restrict__ srcs, const int* __restrict__ dsts,
    const float* __restrict__ w, const float* __restrict__ x,
    float* __restrict__ out, int E) {
  long t = (long)blockIdx.x * 256 + threadIdx.x;
  long e = t >> 6;
  if (e >= E) return;
  int j = (int)(t & 63);
  int s = srcs[e];
  int d = dsts[e];
  float val = w[e] * x[(long)s * DH + j];
  atomicAdd(&out[(long)d * DH + j], val);
}

// ---------------- host ----------------

static inline size_t align256(size_t x) { return (x + 255) & ~(size_t)255; }

extern "C" void kernel_launch(void* const* d_in, const int* in_sizes, int n_in,
                              void* d_out, int out_size, void* d_ws, size_t ws_size,
                              hipStream_t stream) {
  const int*   edge_index = (const int*)d_in[0];
  const float* edge_w     = (const float*)d_in[1];
  const float* emb        = (const float*)d_in[2];
  const float* W1         = (const float*)d_in[3];
  const float* b1         = (const float*)d_in[4];
  const float* W2         = (const float*)d_in[5];
  const float* b2         = (const float*)d_in[6];
  float* out = (float*)d_out;

  const int E = in_sizes[0] / 2;
  const int N = NNODES;
  const int* srcs = edge_index;
  const int* dsts = edge_index + E;

  const size_t pairs2bytes = (size_t)N * NODECAP * sizeof(int);        // 25.6 MB
  const size_t xbytes_bf   = (size_t)N * DH * sizeof(__hip_bfloat16);  // 12.8 MB
  const size_t degbytes    = (size_t)(N + 1) * sizeof(int);            // deg + ovfcnt
  const size_t ovfbytes    = (size_t)OVFCAP * sizeof(int2);

  const int aggBlocks = (N + 3) / 4;
  const int gemmBlocks = (N + 127) / 128;   // 128 rows per block (4 waves x 32 rows)

  size_t off = 0;
  char* base = (char*)d_ws;
  int* pairs2 = (int*)(base + off);            off = align256(off + pairs2bytes);
  __hip_bfloat16* xbuf = (__hip_bfloat16*)(base + off); off = align256(off + xbytes_bf);
  int* deg    = (int*)(base + off);            off = align256(off + degbytes);
  int2* ovf   = (int2*)(base + off);           off = align256(off + ovfbytes);
  int* ovfcnt = deg + N;
  const size_t needed_full = off;

  if (ws_size >= needed_full) {
    // ---- direct-binned adjacency build (once, reused by both layers) ----
    hipMemsetAsync(deg, 0, degbytes, stream);
    int scatBlocks = ((E + 3) / 4 + 255) / 256;
    scatter_fill<<<scatBlocks, 256, 0, stream>>>(srcs, dsts, edge_w, deg, pairs2,
                                                 ovf, ovfcnt, E);

    // ---- layer 1: x1 = bf16(emb@W1); agg1 = A@x1 (into d_out, f32) ----
    gemm1_mfma<<<gemmBlocks, 256, 0, stream>>>(emb, W1, xbuf, N);
    agg_quad<<<aggBlocks, 256, 0, stream>>>(pairs2, deg, (const uint2*)xbuf, nullptr, out, N);
    ovf_fixup<<<8, 256, 0, stream>>>(ovf, ovfcnt, (const short*)xbuf, out);

    // ---- layer 2: x2 = bf16(relu(agg1+b1)@W2); out = A@x2 + b2 ----
    gemm2_mfma<<<gemmBlocks, 256, 0, stream>>>(out, W2, b1, xbuf, N);
    agg_quad<<<aggBlocks, 256, 0, stream>>>(pairs2, deg, (const uint2*)xbuf, b2, out, N);
    ovf_fixup<<<8, 256, 0, stream>>>(ovf, ovfcnt, (const short*)xbuf, out);
    return;
  }

  // ---- R1 fallback: atomic scatter (needs only N*64 f32) ----
  const long scatterThreads = (long)E * 64;
  const int scatterBlocks = (int)((scatterThreads + 255) / 256);
  const int rowBlocks4 = (N + 3) / 4;
  float* xb1 = (float*)d_ws;

  gemm1_f32<<<rowBlocks4, 256, 0, stream>>>(emb, W1, xb1, N);
  hipMemsetAsync(d_out, 0, (size_t)N * DH * sizeof(float), stream);
  scatter_kernel<<<scatterBlocks, 256, 0, stream>>>(srcs, dsts, edge_w, xb1, out, E);

  gemm2_f32<<<rowBlocks4, 256, 0, stream>>>(out, W2, b1, xb1, N);
  init_bias_kernel<<<(N * DH + 255) / 256, 256, 0, stream>>>(out, b2, N * DH);
  scatter_kernel<<<scatterBlocks, 256, 0, stream>>>(srcs, dsts, edge_w, xb1, out, E);
}

// Round 4
// 228.847 us; speedup vs baseline: 1.7408x; 1.7408x over previous
//
#include <hip/hip_runtime.h>
#include <hip/hip_bf16.h>

#define NNODES 100000
#define DIN 128
#define DH 64
#define SRCMASK 0x1FFFF                     // N < 2^17
#define BSH2 8
#define BN2 256                             // nodes per bucket
#define NBUCK2 ((NNODES + BN2 - 1) >> BSH2) // 391
#define NCAP 9216                           // slots per bucket (mean 8192, sigma 90)
#define OVFCAP 4096

typedef short s16x8 __attribute__((ext_vector_type(8)));
typedef float f32x4 __attribute__((ext_vector_type(4)));

static __device__ __forceinline__ short f2bf(float f) {
  __hip_bfloat16 h = __float2bfloat16(f);   // RTNE
  return *reinterpret_cast<short*>(&h);
}
static __device__ __forceinline__ float bf2f(short s) {
  return __uint_as_float(((unsigned)(unsigned short)s) << 16);
}

// ---------------- dense transforms via MFMA (hi/lo bf16 split ~ 17-bit mantissa) ----------------
// mfma_f32_16x16x32_bf16 layouts (m89-verified):
//   A: row = lane&15, k = (lane>>4)*8 + i
//   B: col = lane&15, k = (lane>>4)*8 + i
//   D: col = lane&15, row = (lane>>4)*4 + reg

__global__ __launch_bounds__(256, 4) void gemm1_mfma(
    const float* __restrict__ emb, const float* __restrict__ W1,
    __hip_bfloat16* __restrict__ x1, int N) {
  __shared__ short Bhi[4 * 4 * 64 * 8];   // 16 KB
  __shared__ short Blo[4 * 4 * 64 * 8];   // 16 KB
  int tid = threadIdx.x;

  for (int idx = tid; idx < 8192; idx += 256) {
    int i = idx & 7, ln = (idx >> 3) & 63, ct = (idx >> 9) & 3, kc = idx >> 11;
    int k = kc * 32 + (ln >> 4) * 8 + i;
    int col = ct * 16 + (ln & 15);
    float w = W1[k * DH + col];
    short h = f2bf(w);
    Bhi[idx] = h;
    Blo[idx] = f2bf(w - bf2f(h));
  }
  __syncthreads();

  int lane = tid & 63, wv = tid >> 6;
  int r0 = (blockIdx.x * 8 + wv * 2) * 16;   // this wave: rows r0 .. r0+31
  if (r0 >= N) return;

  const int rA = lane & 15, g = lane >> 4;
  f32x4 acc[2][4] = {};

#pragma unroll
  for (int kc = 0; kc < 4; ++kc) {
    s16x8 ahi[2], alo[2];
#pragma unroll
    for (int rt = 0; rt < 2; ++rt) {
      int r = r0 + rt * 16 + rA;
      float av[8];
      if (r < N) {
        const float4* ap = (const float4*)(emb + (long)r * DIN + kc * 32 + g * 8);
        float4 v0 = ap[0], v1 = ap[1];
        av[0] = v0.x; av[1] = v0.y; av[2] = v0.z; av[3] = v0.w;
        av[4] = v1.x; av[5] = v1.y; av[6] = v1.z; av[7] = v1.w;
      } else {
#pragma unroll
        for (int i = 0; i < 8; ++i) av[i] = 0.f;
      }
#pragma unroll
      for (int i = 0; i < 8; ++i) {
        short h = f2bf(av[i]);
        ahi[rt][i] = h;
        alo[rt][i] = f2bf(av[i] - bf2f(h));
      }
    }
#pragma unroll
    for (int ct = 0; ct < 4; ++ct) {
      int fo = ((kc * 4 + ct) * 64 + lane) * 8;
      s16x8 bh = *(const s16x8*)&Bhi[fo];
      s16x8 bl = *(const s16x8*)&Blo[fo];
#pragma unroll
      for (int rt = 0; rt < 2; ++rt) {
        acc[rt][ct] = __builtin_amdgcn_mfma_f32_16x16x32_bf16(ahi[rt], bh, acc[rt][ct], 0, 0, 0);
        acc[rt][ct] = __builtin_amdgcn_mfma_f32_16x16x32_bf16(alo[rt], bh, acc[rt][ct], 0, 0, 0);
        acc[rt][ct] = __builtin_amdgcn_mfma_f32_16x16x32_bf16(ahi[rt], bl, acc[rt][ct], 0, 0, 0);
      }
    }
  }

#pragma unroll
  for (int rt = 0; rt < 2; ++rt) {
#pragma unroll
    for (int j = 0; j < 4; ++j) {
      int row = r0 + rt * 16 + g * 4 + j;
      if (row < N) {
#pragma unroll
        for (int ct = 0; ct < 4; ++ct)
          x1[(long)row * DH + ct * 16 + rA] = __float2bfloat16(acc[rt][ct][j]);
      }
    }
  }
}

__global__ __launch_bounds__(256, 4) void gemm2_mfma(
    const float* __restrict__ agg, const float* __restrict__ W2,
    const float* __restrict__ b1, __hip_bfloat16* __restrict__ x2, int N) {
  __shared__ short Bhi[2 * 4 * 64 * 8];   // 8 KB
  __shared__ short Blo[2 * 4 * 64 * 8];   // 8 KB
  int tid = threadIdx.x;

  for (int idx = tid; idx < 4096; idx += 256) {
    int i = idx & 7, ln = (idx >> 3) & 63, ct = (idx >> 9) & 3, kc = (idx >> 11) & 1;
    int k = kc * 32 + (ln >> 4) * 8 + i;
    int col = ct * 16 + (ln & 15);
    float w = W2[k * DH + col];
    short h = f2bf(w);
    Bhi[idx] = h;
    Blo[idx] = f2bf(w - bf2f(h));
  }
  __syncthreads();

  int lane = tid & 63, wv = tid >> 6;
  int r0 = (blockIdx.x * 8 + wv * 2) * 16;
  if (r0 >= N) return;

  const int rA = lane & 15, g = lane >> 4;
  f32x4 acc[2][4] = {};

#pragma unroll
  for (int kc = 0; kc < 2; ++kc) {
    const float4* bp = (const float4*)(b1 + kc * 32 + g * 8);
    float4 b0 = bp[0], b4 = bp[1];
    float bv[8] = {b0.x, b0.y, b0.z, b0.w, b4.x, b4.y, b4.z, b4.w};
    s16x8 ahi[2], alo[2];
#pragma unroll
    for (int rt = 0; rt < 2; ++rt) {
      int r = r0 + rt * 16 + rA;
      float av[8];
      if (r < N) {
        const float4* ap = (const float4*)(agg + (long)r * DH + kc * 32 + g * 8);
        float4 v0 = ap[0], v1 = ap[1];
        av[0] = v0.x; av[1] = v0.y; av[2] = v0.z; av[3] = v0.w;
        av[4] = v1.x; av[5] = v1.y; av[6] = v1.z; av[7] = v1.w;
      } else {
#pragma unroll
        for (int i = 0; i < 8; ++i) av[i] = -1e30f;  // relu() -> 0 anyway
      }
#pragma unroll
      for (int i = 0; i < 8; ++i) {
        float a = fmaxf(av[i] + bv[i], 0.f);
        short h = f2bf(a);
        ahi[rt][i] = h;
        alo[rt][i] = f2bf(a - bf2f(h));
      }
    }
#pragma unroll
    for (int ct = 0; ct < 4; ++ct) {
      int fo = ((kc * 4 + ct) * 64 + lane) * 8;
      s16x8 bh = *(const s16x8*)&Bhi[fo];
      s16x8 bl = *(const s16x8*)&Blo[fo];
#pragma unroll
      for (int rt = 0; rt < 2; ++rt) {
        acc[rt][ct] = __builtin_amdgcn_mfma_f32_16x16x32_bf16(ahi[rt], bh, acc[rt][ct], 0, 0, 0);
        acc[rt][ct] = __builtin_amdgcn_mfma_f32_16x16x32_bf16(alo[rt], bh, acc[rt][ct], 0, 0, 0);
        acc[rt][ct] = __builtin_amdgcn_mfma_f32_16x16x32_bf16(ahi[rt], bl, acc[rt][ct], 0, 0, 0);
      }
    }
  }

#pragma unroll
  for (int rt = 0; rt < 2; ++rt) {
#pragma unroll
    for (int j = 0; j < 4; ++j) {
      int row = r0 + rt * 16 + g * 4 + j;
      if (row < N) {
#pragma unroll
        for (int ct = 0; ct < 4; ++ct)
          x2[(long)row * DH + ct * 16 + rA] = __float2bfloat16(acc[rt][ct][j]);
      }
    }
  }
}

// ---------------- 2-kernel bucketed build (fixed-capacity buckets, no hist/scan) --------------
// fill_direct: chunk-reserved bucket binning. esw4 = src(17b) | dlow(8b)<<17; w16 = w*2^15.
// Bucket b owns region [b*NCAP, (b+1)*NCAP); overflow (statistically ~never) -> ovf list.

__global__ __launch_bounds__(512) void fill_direct(
    const int* __restrict__ srcs, const int* __restrict__ dsts,
    const float* __restrict__ w, int* __restrict__ bCnt,
    int* __restrict__ esw4, unsigned short* __restrict__ w16,
    int2* __restrict__ ovf, int* __restrict__ ovfcnt, int E) {
  __shared__ int cnt[NBUCK2];
  __shared__ int base[NBUCK2];
  int tid = threadIdx.x;
  for (int i = tid; i < NBUCK2; i += 512) cnt[i] = 0;
  __syncthreads();
  int e0 = blockIdx.x * 8192;
  int pk[16]; int bs[16]; int wq[16]; int dd[16];
#pragma unroll
  for (int i = 0; i < 16; ++i) {
    int e = e0 + tid + i * 512;
    if (e < E) {
      int s = srcs[e], d = dsts[e];
      float wv = w[e];
      int q = (int)(wv * 32768.f + 0.5f);
      if (q > 32767) q = 32767;
      pk[i] = (s & SRCMASK) | ((d & (BN2 - 1)) << 17);
      wq[i] = q;
      bs[i] = d >> BSH2;
      dd[i] = d;
    } else { bs[i] = -1; pk[i] = 0; wq[i] = 0; dd[i] = 0; }
  }
#pragma unroll
  for (int i = 0; i < 16; ++i)
    if (bs[i] >= 0) atomicAdd(&cnt[bs[i]], 1);
  __syncthreads();
  for (int b = tid; b < NBUCK2; b += 512)
    base[b] = cnt[b] ? atomicAdd(&bCnt[b], cnt[b]) : 0;
  __syncthreads();
  for (int i = tid; i < NBUCK2; i += 512) cnt[i] = 0;
  __syncthreads();
#pragma unroll
  for (int i = 0; i < 16; ++i) {
    if (bs[i] >= 0) {
      int pos = base[bs[i]] + atomicAdd(&cnt[bs[i]], 1);
      if (pos < NCAP) {
        int g = bs[i] * NCAP + pos;
        esw4[g] = pk[i];
        w16[g] = (unsigned short)wq[i];
      } else {
        int oi = atomicAdd(ovfcnt, 1);
        if (oi < OVFCAP) ovf[oi] = make_int2((pk[i] & SRCMASK) | (wq[i] << 17), dd[i]);
      }
    }
  }
}

// one block per bucket: LDS hist + scan + scatter into packed pairs; writes noff/ndeg.
__global__ __launch_bounds__(256) void csr_build2(
    const int* __restrict__ bCnt, const int* __restrict__ esw4,
    const unsigned short* __restrict__ w16,
    int* __restrict__ noff, int* __restrict__ ndeg,
    int* __restrict__ pairs, int N) {
  int b = blockIdx.x;
  int nb0 = b << BSH2;
  int cnt = bCnt[b];
  if (cnt > NCAP) cnt = NCAP;
  int st = b * NCAP;
  __shared__ int deg[BN2];
  __shared__ int cur[BN2];
  int tid = threadIdx.x;
  deg[tid] = 0;
  __syncthreads();
  for (int k = st + tid; k < st + cnt; k += 256)
    atomicAdd(&deg[(esw4[k] >> 17) & (BN2 - 1)], 1);
  __syncthreads();
  int v = deg[tid];
  cur[tid] = v;
  __syncthreads();
  for (int d = 1; d < 256; d <<= 1) {
    int u = (tid >= d) ? cur[tid - d] : 0;
    __syncthreads();
    cur[tid] += u;
    __syncthreads();
  }
  int lo = st + cur[tid] - v;
  cur[tid] = lo;
  int n = nb0 + tid;
  if (n < N) { noff[n] = lo; ndeg[n] = v; }
  __syncthreads();
  for (int k = st + tid; k < st + cnt; k += 256) {
    int e = esw4[k];
    int p = atomicAdd(&cur[(e >> 17) & (BN2 - 1)], 1);
    pairs[p] = (e & SRCMASK) | ((int)w16[k] << 17);
  }
}

// applies overflow edges (bucket overflow; ~never) after an agg pass
__global__ __launch_bounds__(256) void ovf_fixup(
    const int2* __restrict__ ovf, const int* __restrict__ ovfcnt,
    const short* __restrict__ x, float* __restrict__ out) {
  int cnt = *ovfcnt;
  if (cnt > OVFCAP) cnt = OVFCAP;
  int wid = (int)((blockIdx.x * 256 + threadIdx.x) >> 6);
  int lane = threadIdx.x & 63;
  int nw = (gridDim.x * 256) >> 6;
  for (int i = wid; i < cnt; i += nw) {
    int2 e = ovf[i];
    unsigned p = (unsigned)e.x;
    float wv = (float)(p >> 17) * (1.f / 32768.f);
    float xv = bf2f(x[(long)(p & SRCMASK) * DH + lane]);
    atomicAdd(&out[(long)e.y * DH + lane], wv * xv);
  }
}

// ---------------- aggregation: deep-MLP gather ----------------
// lane = h*16 + fj : h = edge-of-quad (0..3), fj = feature-quad (0..15).
#define ACC4(P, XV)                                          \
  do {                                                       \
    float wv_ = (float)((P) >> 17) * (1.f / 32768.f);        \
    a0 += wv_ * __uint_as_float((XV).x << 16);               \
    a1 += wv_ * __uint_as_float((XV).x & 0xFFFF0000u);       \
    a2 += wv_ * __uint_as_float((XV).y << 16);               \
    a3 += wv_ * __uint_as_float((XV).y & 0xFFFF0000u);       \
  } while (0)

__global__ __launch_bounds__(256) void agg_quad(
    const int* __restrict__ pairs, const int* __restrict__ noff,
    const int* __restrict__ ndeg,
    const uint2* __restrict__ x,   // 4×bf16 per element, 16 per node
    const float* __restrict__ bias, float* __restrict__ out, int N) {
  int wid = (int)(((long)blockIdx.x * 256 + threadIdx.x) >> 6);
  int lane = threadIdx.x & 63;
  if (wid >= N) return;
  int h = lane >> 4;        // edge within quad
  int fj = lane & 15;       // feature-quad index
  int st = noff[wid];
  int m = ndeg[wid];
  float a0 = 0.f, a1 = 0.f, a2 = 0.f, a3 = 0.f;

  for (int base = 0; base < m; base += 64) {
    int pl = (base + lane < m) ? pairs[st + base + lane] : 0;  // coalesced, padded
    int mm = m - base;

    // edges base+0 .. base+31: 8 independent gathers in flight
    unsigned pg[8];
#pragma unroll
    for (int g = 0; g < 8; ++g) pg[g] = (unsigned)__shfl(pl, g * 4 + h);
    uint2 xg[8];
#pragma unroll
    for (int g = 0; g < 8; ++g) xg[g] = x[(pg[g] & SRCMASK) * 16 + fj];
#pragma unroll
    for (int g = 0; g < 8; ++g) ACC4(pg[g], xg[g]);

    // edges base+32 .. base+63: 16-edge steps, wave-uniform early exit
#pragma unroll
    for (int q = 32; q < 64; q += 16) {
      if (q >= mm) break;
      unsigned p0 = (unsigned)__shfl(pl, q + h);
      unsigned p1 = (unsigned)__shfl(pl, q + 4 + h);
      unsigned p2 = (unsigned)__shfl(pl, q + 8 + h);
      unsigned p3 = (unsigned)__shfl(pl, q + 12 + h);
      uint2 y0 = x[(p0 & SRCMASK) * 16 + fj];
      uint2 y1 = x[(p1 & SRCMASK) * 16 + fj];
      uint2 y2 = x[(p2 & SRCMASK) * 16 + fj];
      uint2 y3 = x[(p3 & SRCMASK) * 16 + fj];
      ACC4(p0, y0); ACC4(p1, y1); ACC4(p2, y2); ACC4(p3, y3);
    }
  }

  // sum over the 4 edge-groups (h); lanes with equal fj hold same features
  a0 += __shfl_xor(a0, 16); a0 += __shfl_xor(a0, 32);
  a1 += __shfl_xor(a1, 16); a1 += __shfl_xor(a1, 32);
  a2 += __shfl_xor(a2, 16); a2 += __shfl_xor(a2, 32);
  a3 += __shfl_xor(a3, 16); a3 += __shfl_xor(a3, 32);
  if (lane < 16) {
    if (bias) {
      float4 bv = ((const float4*)bias)[fj];
      a0 += bv.x; a1 += bv.y; a2 += bv.z; a3 += bv.w;
    }
    ((float4*)out)[(long)wid * 16 + fj] = make_float4(a0, a1, a2, a3);
  }
}

// ---------------- fallback kernels (R1 atomic path, f32) ----------------

__global__ __launch_bounds__(256) void gemm1_f32(
    const float* __restrict__ emb, const float* __restrict__ W1,
    float* __restrict__ x1, int N) {
  __shared__ float Ws[DIN * DH];
  __shared__ float rows[4][DIN];
  int tid = threadIdx.x;
  for (int i = tid; i < DIN * DH; i += 256) Ws[i] = W1[i];
  int r0 = blockIdx.x * 4;
  for (int i = tid; i < 4 * DIN; i += 256) {
    int rr = i >> 7, kk = i & 127;
    int r = r0 + rr;
    rows[rr][kk] = (r < N) ? emb[(long)r * DIN + kk] : 0.f;
  }
  __syncthreads();
  int rr = tid >> 6, j = tid & 63;
  int r = r0 + rr;
  float acc = 0.f;
#pragma unroll
  for (int k = 0; k < DIN; ++k) acc += rows[rr][k] * Ws[k * DH + j];
  if (r < N) x1[(long)r * DH + j] = acc;
}

__global__ __launch_bounds__(256) void gemm2_f32(
    const float* __restrict__ agg, const float* __restrict__ W2,
    const float* __restrict__ b1, float* __restrict__ x2, int N) {
  __shared__ float Ws[DH * DH];
  __shared__ float rows[4][DH];
  int tid = threadIdx.x;
  for (int i = tid; i < DH * DH; i += 256) Ws[i] = W2[i];
  int r0 = blockIdx.x * 4;
  {
    int rr = tid >> 6, kk = tid & 63;
    int r = r0 + rr;
    float v = (r < N) ? agg[(long)r * DH + kk] + b1[kk] : 0.f;
    rows[rr][kk] = v > 0.f ? v : 0.f;
  }
  __syncthreads();
  int rr = tid >> 6, j = tid & 63;
  float acc = 0.f;
#pragma unroll
  for (int k = 0; k < DH; ++k) acc += rows[rr][k] * Ws[k * DH + j];
  int r = r0 + rr;
  if (r < N) x2[(long)r * DH + j] = acc;
}

__global__ __launch_bounds__(256) void init_bias_kernel(
    float* __restrict__ out, const float* __restrict__ b2, int total) {
  int i = blockIdx.x * 256 + threadIdx.x;
  if (i < total) out[i] = b2[i & 63];
}

__global__ __launch_bounds__(256) void scatter_kernel(
    const int* __restrict__ srcs, const int* __restrict__ dsts,
    const float* __restrict__ w, const float* __restrict__ x,
    float* __restrict__ out, int E) {
  long t = (long)blockIdx.x * 256 + threadIdx.x;
  long e = t >> 6;
  if (e >= E) return;
  int j = (int)(t & 63);
  int s = srcs[e];
  int d = dsts[e];
  float val = w[e] * x[(long)s * DH + j];
  atomicAdd(&out[(long)d * DH + j], val);
}

// ---------------- host ----------------

static inline size_t align256(size_t x) { return (x + 255) & ~(size_t)255; }

extern "C" void kernel_launch(void* const* d_in, const int* in_sizes, int n_in,
                              void* d_out, int out_size, void* d_ws, size_t ws_size,
                              hipStream_t stream) {
  const int*   edge_index = (const int*)d_in[0];
  const float* edge_w     = (const float*)d_in[1];
  const float* emb        = (const float*)d_in[2];
  const float* W1         = (const float*)d_in[3];
  const float* b1         = (const float*)d_in[4];
  const float* W2         = (const float*)d_in[5];
  const float* b2         = (const float*)d_in[6];
  float* out = (float*)d_out;

  const int E = in_sizes[0] / 2;
  const int N = NNODES;
  const int* srcs = edge_index;
  const int* dsts = edge_index + E;

  const size_t esw4bytes  = (size_t)NBUCK2 * NCAP * sizeof(int);        // 14.4 MB
  const size_t w16bytes   = (size_t)NBUCK2 * NCAP * sizeof(unsigned short); // 7.2 MB
  const size_t pairsbytes = (size_t)NBUCK2 * NCAP * sizeof(int);        // 14.4 MB
  const size_t xbytes_bf  = (size_t)N * DH * sizeof(__hip_bfloat16);    // 12.8 MB
  const size_t nbytes     = (size_t)N * sizeof(int);

  const int aggBlocks = (N + 3) / 4;
  const int gemmBlocks = (N + 127) / 128;   // 128 rows per block (4 waves x 32 rows)

  size_t off = 0;
  char* base = (char*)d_ws;
  int* esw4 = (int*)(base + off);
  off = align256(off + (esw4bytes > xbytes_bf ? esw4bytes : xbytes_bf));
  __hip_bfloat16* xbuf = (__hip_bfloat16*)esw4;   // alias: esw4 dead after csr_build2
  unsigned short* w16 = (unsigned short*)(base + off); off = align256(off + w16bytes);
  int* pairs = (int*)(base + off);  off = align256(off + pairsbytes);
  int* noff  = (int*)(base + off);  off = align256(off + nbytes);
  int* ndeg  = (int*)(base + off);  off = align256(off + nbytes);
  int* bCnt  = (int*)(base + off);  off = align256(off + (NBUCK2 + 1) * sizeof(int));
  int2* ovf  = (int2*)(base + off); off = align256(off + OVFCAP * sizeof(int2));
  int* ovfcnt = bCnt + NBUCK2;
  const size_t needed_full = off;

  if (ws_size >= needed_full) {
    // ---- 2-kernel bucketed build (once, reused by both layers) ----
    hipMemsetAsync(bCnt, 0, (NBUCK2 + 1) * sizeof(int), stream);
    fill_direct<<<(E + 8191) / 8192, 512, 0, stream>>>(srcs, dsts, edge_w, bCnt,
                                                       esw4, w16, ovf, ovfcnt, E);
    csr_build2<<<NBUCK2, 256, 0, stream>>>(bCnt, esw4, w16, noff, ndeg, pairs, N);

    // ---- layer 1: x1 = bf16(emb@W1); agg1 = A@x1 (into d_out, f32) ----
    gemm1_mfma<<<gemmBlocks, 256, 0, stream>>>(emb, W1, xbuf, N);
    agg_quad<<<aggBlocks, 256, 0, stream>>>(pairs, noff, ndeg, (const uint2*)xbuf,
                                            nullptr, out, N);
    ovf_fixup<<<8, 256, 0, stream>>>(ovf, ovfcnt, (const short*)xbuf, out);

    // ---- layer 2: x2 = bf16(relu(agg1+b1)@W2); out = A@x2 + b2 ----
    gemm2_mfma<<<gemmBlocks, 256, 0, stream>>>(out, W2, b1, xbuf, N);
    agg_quad<<<aggBlocks, 256, 0, stream>>>(pairs, noff, ndeg, (const uint2*)xbuf,
                                            b2, out, N);
    ovf_fixup<<<8, 256, 0, stream>>>(ovf, ovfcnt, (const short*)xbuf, out);
    return;
  }

  // ---- R1 fallback: atomic scatter (needs only N*64 f32) ----
  const long scatterThreads = (long)E * 64;
  const int scatterBlocks = (int)((scatterThreads + 255) / 256);
  const int rowBlocks4 = (N + 3) / 4;
  float* xb1 = (float*)d_ws;

  gemm1_f32<<<rowBlocks4, 256, 0, stream>>>(emb, W1, xb1, N);
  hipMemsetAsync(d_out, 0, (size_t)N * DH * sizeof(float), stream);
  scatter_kernel<<<scatterBlocks, 256, 0, stream>>>(srcs, dsts, edge_w, xb1, out, E);

  gemm2_f32<<<rowBlocks4, 256, 0, stream>>>(out, W2, b1, xb1, N);
  init_bias_kernel<<<(N * DH + 255) / 256, 256, 0, stream>>>(out, b2, N * DH);
  scatter_kernel<<<scatterBlocks, 256, 0, stream>>>(srcs, dsts, edge_w, xb1, out, E);
}

// Round 5
// 200.804 us; speedup vs baseline: 1.9839x; 1.1397x over previous
//
#include <hip/hip_runtime.h>
#include <hip/hip_bf16.h>

#define NNODES 100000
#define DIN 128
#define DH 64
#define SRCMASK 0x1FFFF                     // N < 2^17
#define BSH2 8
#define BN2 256                             // nodes per bucket
#define NBUCK2 ((NNODES + BN2 - 1) >> BSH2) // 391
#define NCAP 9088                           // slots per bucket (mean 8192, sigma ~90)
#define EPB 8192                            // edges per block_sort block
#define MAXBLK 512                          // max source blocks (E <= 4.19M)
#define OVFCAP 4096

typedef short s16x8 __attribute__((ext_vector_type(8)));
typedef float f32x4 __attribute__((ext_vector_type(4)));

static __device__ __forceinline__ short f2bf(float f) {
  __hip_bfloat16 h = __float2bfloat16(f);   // RTNE
  return *reinterpret_cast<short*>(&h);
}
static __device__ __forceinline__ float bf2f(short s) {
  return __uint_as_float(((unsigned)(unsigned short)s) << 16);
}

// ---------------- dense transforms via MFMA (hi/lo bf16 split ~ 17-bit mantissa) ----------------
// mfma_f32_16x16x32_bf16 layouts (m89-verified):
//   A: row = lane&15, k = (lane>>4)*8 + i
//   B: col = lane&15, k = (lane>>4)*8 + i
//   D: col = lane&15, row = (lane>>4)*4 + reg

__global__ __launch_bounds__(256, 4) void gemm1_mfma(
    const float* __restrict__ emb, const float* __restrict__ W1,
    __hip_bfloat16* __restrict__ x1, int N) {
  __shared__ short Bhi[4 * 4 * 64 * 8];   // 16 KB
  __shared__ short Blo[4 * 4 * 64 * 8];   // 16 KB
  int tid = threadIdx.x;

  for (int idx = tid; idx < 8192; idx += 256) {
    int i = idx & 7, ln = (idx >> 3) & 63, ct = (idx >> 9) & 3, kc = idx >> 11;
    int k = kc * 32 + (ln >> 4) * 8 + i;
    int col = ct * 16 + (ln & 15);
    float w = W1[k * DH + col];
    short h = f2bf(w);
    Bhi[idx] = h;
    Blo[idx] = f2bf(w - bf2f(h));
  }
  __syncthreads();

  int lane = tid & 63, wv = tid >> 6;
  int r0 = (blockIdx.x * 8 + wv * 2) * 16;   // this wave: rows r0 .. r0+31
  if (r0 >= N) return;

  const int rA = lane & 15, g = lane >> 4;
  f32x4 acc[2][4] = {};

#pragma unroll
  for (int kc = 0; kc < 4; ++kc) {
    s16x8 ahi[2], alo[2];
#pragma unroll
    for (int rt = 0; rt < 2; ++rt) {
      int r = r0 + rt * 16 + rA;
      float av[8];
      if (r < N) {
        const float4* ap = (const float4*)(emb + (long)r * DIN + kc * 32 + g * 8);
        float4 v0 = ap[0], v1 = ap[1];
        av[0] = v0.x; av[1] = v0.y; av[2] = v0.z; av[3] = v0.w;
        av[4] = v1.x; av[5] = v1.y; av[6] = v1.z; av[7] = v1.w;
      } else {
#pragma unroll
        for (int i = 0; i < 8; ++i) av[i] = 0.f;
      }
#pragma unroll
      for (int i = 0; i < 8; ++i) {
        short h = f2bf(av[i]);
        ahi[rt][i] = h;
        alo[rt][i] = f2bf(av[i] - bf2f(h));
      }
    }
#pragma unroll
    for (int ct = 0; ct < 4; ++ct) {
      int fo = ((kc * 4 + ct) * 64 + lane) * 8;
      s16x8 bh = *(const s16x8*)&Bhi[fo];
      s16x8 bl = *(const s16x8*)&Blo[fo];
#pragma unroll
      for (int rt = 0; rt < 2; ++rt) {
        acc[rt][ct] = __builtin_amdgcn_mfma_f32_16x16x32_bf16(ahi[rt], bh, acc[rt][ct], 0, 0, 0);
        acc[rt][ct] = __builtin_amdgcn_mfma_f32_16x16x32_bf16(alo[rt], bh, acc[rt][ct], 0, 0, 0);
        acc[rt][ct] = __builtin_amdgcn_mfma_f32_16x16x32_bf16(ahi[rt], bl, acc[rt][ct], 0, 0, 0);
      }
    }
  }

#pragma unroll
  for (int rt = 0; rt < 2; ++rt) {
#pragma unroll
    for (int j = 0; j < 4; ++j) {
      int row = r0 + rt * 16 + g * 4 + j;
      if (row < N) {
#pragma unroll
        for (int ct = 0; ct < 4; ++ct)
          x1[(long)row * DH + ct * 16 + rA] = __float2bfloat16(acc[rt][ct][j]);
      }
    }
  }
}

__global__ __launch_bounds__(256, 4) void gemm2_mfma(
    const float* __restrict__ agg, const float* __restrict__ W2,
    const float* __restrict__ b1, __hip_bfloat16* __restrict__ x2, int N) {
  __shared__ short Bhi[2 * 4 * 64 * 8];   // 8 KB
  __shared__ short Blo[2 * 4 * 64 * 8];   // 8 KB
  int tid = threadIdx.x;

  for (int idx = tid; idx < 4096; idx += 256) {
    int i = idx & 7, ln = (idx >> 3) & 63, ct = (idx >> 9) & 3, kc = (idx >> 11) & 1;
    int k = kc * 32 + (ln >> 4) * 8 + i;
    int col = ct * 16 + (ln & 15);
    float w = W2[k * DH + col];
    short h = f2bf(w);
    Bhi[idx] = h;
    Blo[idx] = f2bf(w - bf2f(h));
  }
  __syncthreads();

  int lane = tid & 63, wv = tid >> 6;
  int r0 = (blockIdx.x * 8 + wv * 2) * 16;
  if (r0 >= N) return;

  const int rA = lane & 15, g = lane >> 4;
  f32x4 acc[2][4] = {};

#pragma unroll
  for (int kc = 0; kc < 2; ++kc) {
    const float4* bp = (const float4*)(b1 + kc * 32 + g * 8);
    float4 b0 = bp[0], b4 = bp[1];
    float bv[8] = {b0.x, b0.y, b0.z, b0.w, b4.x, b4.y, b4.z, b4.w};
    s16x8 ahi[2], alo[2];
#pragma unroll
    for (int rt = 0; rt < 2; ++rt) {
      int r = r0 + rt * 16 + rA;
      float av[8];
      if (r < N) {
        const float4* ap = (const float4*)(agg + (long)r * DH + kc * 32 + g * 8);
        float4 v0 = ap[0], v1 = ap[1];
        av[0] = v0.x; av[1] = v0.y; av[2] = v0.z; av[3] = v0.w;
        av[4] = v1.x; av[5] = v1.y; av[6] = v1.z; av[7] = v1.w;
      } else {
#pragma unroll
        for (int i = 0; i < 8; ++i) av[i] = -1e30f;  // relu() -> 0 anyway
      }
#pragma unroll
      for (int i = 0; i < 8; ++i) {
        float a = fmaxf(av[i] + bv[i], 0.f);
        short h = f2bf(a);
        ahi[rt][i] = h;
        alo[rt][i] = f2bf(a - bf2f(h));
      }
    }
#pragma unroll
    for (int ct = 0; ct < 4; ++ct) {
      int fo = ((kc * 4 + ct) * 64 + lane) * 8;
      s16x8 bh = *(const s16x8*)&Bhi[fo];
      s16x8 bl = *(const s16x8*)&Blo[fo];
#pragma unroll
      for (int rt = 0; rt < 2; ++rt) {
        acc[rt][ct] = __builtin_amdgcn_mfma_f32_16x16x32_bf16(ahi[rt], bh, acc[rt][ct], 0, 0, 0);
        acc[rt][ct] = __builtin_amdgcn_mfma_f32_16x16x32_bf16(alo[rt], bh, acc[rt][ct], 0, 0, 0);
        acc[rt][ct] = __builtin_amdgcn_mfma_f32_16x16x32_bf16(ahi[rt], bl, acc[rt][ct], 0, 0, 0);
      }
    }
  }

#pragma unroll
  for (int rt = 0; rt < 2; ++rt) {
#pragma unroll
    for (int j = 0; j < 4; ++j) {
      int row = r0 + rt * 16 + g * 4 + j;
      if (row < N) {
#pragma unroll
        for (int ct = 0; ct < 4; ++ct)
          x2[(long)row * DH + ct * 16 + rA] = __float2bfloat16(acc[rt][ct][j]);
      }
    }
  }
}

// ---------------- 2-pass counting-sort build, all global writes coalesced ----------------
// Pass 1 (block_sort): each block bucket-sorts its own 8192 edges in LDS and writes them
// to its OWN contiguous region of `sorted` (int2: pk = src|wq<<17, dlow) + a ushort
// offset row offTab[blk][0..NBUCK2] (exclusive scan, last = total).
__global__ __launch_bounds__(512) void block_sort(
    const int* __restrict__ srcs, const int* __restrict__ dsts,
    const float* __restrict__ w, int2* __restrict__ sorted,
    unsigned short* __restrict__ offTab, int E) {
  __shared__ int2 stage[EPB];      // 64 KB
  __shared__ int hist[512];
  __shared__ int sc[512];
  __shared__ int cur[512];
  int tid = threadIdx.x, blk = blockIdx.x;
  int e0 = blk * EPB;

  hist[tid] = 0;
  __syncthreads();

  int pk[16], bd[16];
#pragma unroll
  for (int i = 0; i < 16; ++i) {
    int e = e0 + i * 512 + tid;
    if (e < E) {
      int s = srcs[e], d = dsts[e];
      float wv = w[e];
      int q = (int)(wv * 32768.f + 0.5f);
      if (q > 32767) q = 32767;
      pk[i] = (s & SRCMASK) | (q << 17);
      bd[i] = d;
    } else bd[i] = -1;
  }
#pragma unroll
  for (int i = 0; i < 16; ++i)
    if (bd[i] >= 0) atomicAdd(&hist[bd[i] >> BSH2], 1);
  __syncthreads();

  sc[tid] = (tid < NBUCK2) ? hist[tid] : 0;
  __syncthreads();
  for (int d = 1; d < 512; d <<= 1) {
    int u = (tid >= d) ? sc[tid - d] : 0;
    __syncthreads();
    sc[tid] += u;
    __syncthreads();
  }
  long row = (long)blk * (NBUCK2 + 1);
  if (tid < NBUCK2) {
    int base = sc[tid] - hist[tid];
    cur[tid] = base;
    offTab[row + tid] = (unsigned short)base;
    if (tid == NBUCK2 - 1) offTab[row + NBUCK2] = (unsigned short)sc[tid];
  }
  __syncthreads();

#pragma unroll
  for (int i = 0; i < 16; ++i) {
    if (bd[i] >= 0) {
      int pos = atomicAdd(&cur[bd[i] >> BSH2], 1);
      stage[pos] = make_int2(pk[i], bd[i] & (BN2 - 1));
    }
  }
  __syncthreads();

  int eN = min(EPB, E - e0);
  for (int i = tid; i < eN; i += 512)
    sorted[(long)blk * EPB + i] = stage[i];   // fully coalesced
}

// Pass 2 (gather_build): one block per bucket. Gather the bucket's chunks from all
// source-block regions into LDS, per-node hist+scan, write noff/ndeg + dense pairs.
__global__ __launch_bounds__(512) void gather_build(
    const unsigned short* __restrict__ offTab, const int2* __restrict__ sorted,
    int* __restrict__ noff, int* __restrict__ ndeg, int* __restrict__ pairs,
    int2* __restrict__ ovf, int* __restrict__ ovfcnt, int NBLK, int N) {
  __shared__ int2 gath[NCAP];             // 71 KB
  __shared__ unsigned short offR[MAXBLK]; // 1 KB
  __shared__ unsigned short cntR[MAXBLK]; // 1 KB
  __shared__ int baseR[MAXBLK];           // 2 KB
  __shared__ int sc[512];                 // 2 KB
  __shared__ int deg[BN2], cur[BN2];      // 2 KB
  int b = blockIdx.x, tid = threadIdx.x;

  for (int blk = tid; blk < NBLK; blk += 512) {
    long row = (long)blk * (NBUCK2 + 1);
    int st = offTab[row + b];
    int en = offTab[row + b + 1];
    offR[blk] = (unsigned short)st;
    cntR[blk] = (unsigned short)(en - st);
  }
  __syncthreads();

  sc[tid] = (tid < NBLK) ? (int)cntR[tid] : 0;
  __syncthreads();
  for (int d = 1; d < 512; d <<= 1) {
    int u = (tid >= d) ? sc[tid - d] : 0;
    __syncthreads();
    sc[tid] += u;
    __syncthreads();
  }
  if (tid < NBLK) baseR[tid] = sc[tid] - (int)cntR[tid];
  __syncthreads();
  int total = sc[NBLK - 1];
  int tcl = total > NCAP ? NCAP : total;

  // copy chunks: wave wv handles source blocks wv, wv+8, ...
  int wv = tid >> 6, lane = tid & 63;
  for (int blk = wv; blk < NBLK; blk += 8) {
    int st = offR[blk], c = cntR[blk], gb = baseR[blk];
    for (int l = lane; l < c; l += 64) {
      int2 v = sorted[(long)blk * EPB + st + l];
      int gp = gb + l;
      if (gp < NCAP) gath[gp] = v;
      else {
        int oi = atomicAdd(ovfcnt, 1);
        if (oi < OVFCAP) ovf[oi] = make_int2(v.x, (b << BSH2) | v.y);
      }
    }
  }
  if (tid < BN2) deg[tid] = 0;
  __syncthreads();

  for (int k = tid; k < tcl; k += 512)
    atomicAdd(&deg[gath[k].y & (BN2 - 1)], 1);
  __syncthreads();

  sc[tid] = (tid < BN2) ? deg[tid] : 0;
  __syncthreads();
  for (int d = 1; d < 512; d <<= 1) {
    int u = (tid >= d) ? sc[tid - d] : 0;
    __syncthreads();
    sc[tid] += u;
    __syncthreads();
  }
  if (tid < BN2) {
    int excl = sc[tid] - deg[tid];
    int gpos = b * NCAP + excl;
    cur[tid] = gpos;
    int n = (b << BSH2) + tid;
    if (n < N) { noff[n] = gpos; ndeg[n] = deg[tid]; }
  }
  __syncthreads();

  for (int k = tid; k < tcl; k += 512) {
    int p = atomicAdd(&cur[gath[k].y & (BN2 - 1)], 1);
    pairs[p] = gath[k].x;   // dense 36KB region per bucket -> merges in L2
  }
}

// applies overflow edges (bucket overflow; ~never) after an agg pass
__global__ __launch_bounds__(256) void ovf_fixup(
    const int2* __restrict__ ovf, const int* __restrict__ ovfcnt,
    const short* __restrict__ x, float* __restrict__ out) {
  int cnt = *ovfcnt;
  if (cnt > OVFCAP) cnt = OVFCAP;
  int wid = (int)((blockIdx.x * 256 + threadIdx.x) >> 6);
  int lane = threadIdx.x & 63;
  int nw = (gridDim.x * 256) >> 6;
  for (int i = wid; i < cnt; i += nw) {
    int2 e = ovf[i];
    unsigned p = (unsigned)e.x;
    float wv = (float)(p >> 17) * (1.f / 32768.f);
    float xv = bf2f(x[(long)(p & SRCMASK) * DH + lane]);
    atomicAdd(&out[(long)e.y * DH + lane], wv * xv);
  }
}

// ---------------- aggregation: deep-MLP gather ----------------
// lane = h*16 + fj : h = edge-of-quad (0..3), fj = feature-quad (0..15).
#define ACC4(P, XV)                                          \
  do {                                                       \
    float wv_ = (float)((P) >> 17) * (1.f / 32768.f);        \
    a0 += wv_ * __uint_as_float((XV).x << 16);               \
    a1 += wv_ * __uint_as_float((XV).x & 0xFFFF0000u);       \
    a2 += wv_ * __uint_as_float((XV).y << 16);               \
    a3 += wv_ * __uint_as_float((XV).y & 0xFFFF0000u);       \
  } while (0)

__global__ __launch_bounds__(256) void agg_quad(
    const int* __restrict__ pairs, const int* __restrict__ noff,
    const int* __restrict__ ndeg,
    const uint2* __restrict__ x,   // 4×bf16 per element, 16 per node
    const float* __restrict__ bias, float* __restrict__ out, int N) {
  int wid = (int)(((long)blockIdx.x * 256 + threadIdx.x) >> 6);
  int lane = threadIdx.x & 63;
  if (wid >= N) return;
  int h = lane >> 4;        // edge within quad
  int fj = lane & 15;       // feature-quad index
  int st = noff[wid];
  int m = ndeg[wid];
  float a0 = 0.f, a1 = 0.f, a2 = 0.f, a3 = 0.f;

  for (int base = 0; base < m; base += 64) {
    int pl = (base + lane < m) ? pairs[st + base + lane] : 0;  // coalesced, padded
    int mm = m - base;

    // edges base+0 .. base+31: 8 independent gathers in flight
    unsigned pg[8];
#pragma unroll
    for (int g = 0; g < 8; ++g) pg[g] = (unsigned)__shfl(pl, g * 4 + h);
    uint2 xg[8];
#pragma unroll
    for (int g = 0; g < 8; ++g) xg[g] = x[(pg[g] & SRCMASK) * 16 + fj];
#pragma unroll
    for (int g = 0; g < 8; ++g) ACC4(pg[g], xg[g]);

    // edges base+32 .. base+63: 16-edge steps, wave-uniform early exit
#pragma unroll
    for (int q = 32; q < 64; q += 16) {
      if (q >= mm) break;
      unsigned p0 = (unsigned)__shfl(pl, q + h);
      unsigned p1 = (unsigned)__shfl(pl, q + 4 + h);
      unsigned p2 = (unsigned)__shfl(pl, q + 8 + h);
      unsigned p3 = (unsigned)__shfl(pl, q + 12 + h);
      uint2 y0 = x[(p0 & SRCMASK) * 16 + fj];
      uint2 y1 = x[(p1 & SRCMASK) * 16 + fj];
      uint2 y2 = x[(p2 & SRCMASK) * 16 + fj];
      uint2 y3 = x[(p3 & SRCMASK) * 16 + fj];
      ACC4(p0, y0); ACC4(p1, y1); ACC4(p2, y2); ACC4(p3, y3);
    }
  }

  // sum over the 4 edge-groups (h); lanes with equal fj hold same features
  a0 += __shfl_xor(a0, 16); a0 += __shfl_xor(a0, 32);
  a1 += __shfl_xor(a1, 16); a1 += __shfl_xor(a1, 32);
  a2 += __shfl_xor(a2, 16); a2 += __shfl_xor(a2, 32);
  a3 += __shfl_xor(a3, 16); a3 += __shfl_xor(a3, 32);
  if (lane < 16) {
    if (bias) {
      float4 bv = ((const float4*)bias)[fj];
      a0 += bv.x; a1 += bv.y; a2 += bv.z; a3 += bv.w;
    }
    ((float4*)out)[(long)wid * 16 + fj] = make_float4(a0, a1, a2, a3);
  }
}

// ---------------- fallback kernels (R1 atomic path, f32) ----------------

__global__ __launch_bounds__(256) void gemm1_f32(
    const float* __restrict__ emb, const float* __restrict__ W1,
    float* __restrict__ x1, int N) {
  __shared__ float Ws[DIN * DH];
  __shared__ float rows[4][DIN];
  int tid = threadIdx.x;
  for (int i = tid; i < DIN * DH; i += 256) Ws[i] = W1[i];
  int r0 = blockIdx.x * 4;
  for (int i = tid; i < 4 * DIN; i += 256) {
    int rr = i >> 7, kk = i & 127;
    int r = r0 + rr;
    rows[rr][kk] = (r < N) ? emb[(long)r * DIN + kk] : 0.f;
  }
  __syncthreads();
  int rr = tid >> 6, j = tid & 63;
  int r = r0 + rr;
  float acc = 0.f;
#pragma unroll
  for (int k = 0; k < DIN; ++k) acc += rows[rr][k] * Ws[k * DH + j];
  if (r < N) x1[(long)r * DH + j] = acc;
}

__global__ __launch_bounds__(256) void gemm2_f32(
    const float* __restrict__ agg, const float* __restrict__ W2,
    const float* __restrict__ b1, float* __restrict__ x2, int N) {
  __shared__ float Ws[DH * DH];
  __shared__ float rows[4][DH];
  int tid = threadIdx.x;
  for (int i = tid; i < DH * DH; i += 256) Ws[i] = W2[i];
  int r0 = blockIdx.x * 4;
  {
    int rr = tid >> 6, kk = tid & 63;
    int r = r0 + rr;
    float v = (r < N) ? agg[(long)r * DH + kk] + b1[kk] : 0.f;
    rows[rr][kk] = v > 0.f ? v : 0.f;
  }
  __syncthreads();
  int rr = tid >> 6, j = tid & 63;
  float acc = 0.f;
#pragma unroll
  for (int k = 0; k < DH; ++k) acc += rows[rr][k] * Ws[k * DH + j];
  int r = r0 + rr;
  if (r < N) x2[(long)r * DH + j] = acc;
}

__global__ __launch_bounds__(256) void init_bias_kernel(
    float* __restrict__ out, const float* __restrict__ b2, int total) {
  int i = blockIdx.x * 256 + threadIdx.x;
  if (i < total) out[i] = b2[i & 63];
}

__global__ __launch_bounds__(256) void scatter_kernel(
    const int* __restrict__ srcs, const int* __restrict__ dsts,
    const float* __restrict__ w, const float* __restrict__ x,
    float* __restrict__ out, int E) {
  long t = (long)blockIdx.x * 256 + threadIdx.x;
  long e = t >> 6;
  if (e >= E) return;
  int j = (int)(t & 63);
  int s = srcs[e];
  int d = dsts[e];
  float val = w[e] * x[(long)s * DH + j];
  atomicAdd(&out[(long)d * DH + j], val);
}

// ---------------- host ----------------

static inline size_t align256(size_t x) { return (x + 255) & ~(size_t)255; }

extern "C" void kernel_launch(void* const* d_in, const int* in_sizes, int n_in,
                              void* d_out, int out_size, void* d_ws, size_t ws_size,
                              hipStream_t stream) {
  const int*   edge_index = (const int*)d_in[0];
  const float* edge_w     = (const float*)d_in[1];
  const float* emb        = (const float*)d_in[2];
  const float* b1         = (const float*)d_in[4];
  const float* W1         = (const float*)d_in[3];
  const float* W2         = (const float*)d_in[5];
  const float* b2         = (const float*)d_in[6];
  float* out = (float*)d_out;

  const int E = in_sizes[0] / 2;
  const int N = NNODES;
  const int* srcs = edge_index;
  const int* dsts = edge_index + E;

  const int NBLK = (E + EPB - 1) / EPB;     // 391 for E = 3.2M

  const size_t sortedbytes = (size_t)NBLK * EPB * sizeof(int2);         // 25.6 MB
  const size_t xbytes_bf   = (size_t)N * DH * sizeof(__hip_bfloat16);   // 12.8 MB
  const size_t offTabbytes = (size_t)NBLK * (NBUCK2 + 1) * sizeof(unsigned short);
  const size_t pairsbytes  = (size_t)NBUCK2 * NCAP * sizeof(int);       // 14.2 MB
  const size_t nbytes      = (size_t)N * sizeof(int);

  const int aggBlocks = (N + 3) / 4;
  const int gemmBlocks = (N + 127) / 128;   // 128 rows per block (4 waves x 32 rows)

  size_t off = 0;
  char* base = (char*)d_ws;
  int2* sorted = (int2*)(base + off);
  off = align256(off + (sortedbytes > xbytes_bf ? sortedbytes : xbytes_bf));
  __hip_bfloat16* xbuf = (__hip_bfloat16*)sorted;  // alias: sorted dead after gather_build
  unsigned short* offTab = (unsigned short*)(base + off); off = align256(off + offTabbytes);
  int* pairs = (int*)(base + off);  off = align256(off + pairsbytes);
  int* noff  = (int*)(base + off);  off = align256(off + nbytes);
  int* ndeg  = (int*)(base + off);  off = align256(off + nbytes);
  int2* ovf  = (int2*)(base + off); off = align256(off + OVFCAP * sizeof(int2));
  int* ovfcnt = (int*)(base + off); off = align256(off + 256);
  const size_t needed_full = off;

  if (ws_size >= needed_full && NBLK <= MAXBLK) {
    // ---- 2-pass coalesced counting-sort build (once, reused by both layers) ----
    hipMemsetAsync(ovfcnt, 0, sizeof(int), stream);
    block_sort<<<NBLK, 512, 0, stream>>>(srcs, dsts, edge_w, sorted, offTab, E);
    gather_build<<<NBUCK2, 512, 0, stream>>>(offTab, sorted, noff, ndeg, pairs,
                                             ovf, ovfcnt, NBLK, N);

    // ---- layer 1: x1 = bf16(emb@W1); agg1 = A@x1 (into d_out, f32) ----
    gemm1_mfma<<<gemmBlocks, 256, 0, stream>>>(emb, W1, xbuf, N);
    agg_quad<<<aggBlocks, 256, 0, stream>>>(pairs, noff, ndeg, (const uint2*)xbuf,
                                            nullptr, out, N);
    ovf_fixup<<<8, 256, 0, stream>>>(ovf, ovfcnt, (const short*)xbuf, out);

    // ---- layer 2: x2 = bf16(relu(agg1+b1)@W2); out = A@x2 + b2 ----
    gemm2_mfma<<<gemmBlocks, 256, 0, stream>>>(out, W2, b1, xbuf, N);
    agg_quad<<<aggBlocks, 256, 0, stream>>>(pairs, noff, ndeg, (const uint2*)xbuf,
                                            b2, out, N);
    ovf_fixup<<<8, 256, 0, stream>>>(ovf, ovfcnt, (const short*)xbuf, out);
    return;
  }

  // ---- R1 fallback: atomic scatter (needs only N*64 f32) ----
  const long scatterThreads = (long)E * 64;
  const int scatterBlocks = (int)((scatterThreads + 255) / 256);
  const int rowBlocks4 = (N + 3) / 4;
  float* xb1 = (float*)d_ws;

  gemm1_f32<<<rowBlocks4, 256, 0, stream>>>(emb, W1, xb1, N);
  hipMemsetAsync(d_out, 0, (size_t)N * DH * sizeof(float), stream);
  scatter_kernel<<<scatterBlocks, 256, 0, stream>>>(srcs, dsts, edge_w, xb1, out, E);

  gemm2_f32<<<rowBlocks4, 256, 0, stream>>>(out, W2, b1, xb1, N);
  init_bias_kernel<<<(N * DH + 255) / 256, 256, 0, stream>>>(out, b2, N * DH);
  scatter_kernel<<<scatterBlocks, 256, 0, stream>>>(srcs, dsts, edge_w, xb1, out, E);
}